// Round 2
// baseline (706.110 us; speedup 1.0000x reference)
//
#include <hip/hip_runtime.h>
#include <math.h>

#define Bn 4
#define Vn 5
#define Cc 32
#define Hh 256
#define Ww 320
#define DD 4
#define GG 8
#define HW (Hh*Ww)
#define PIXBLK (HW/256)          // 320 pixel-blocks per (b,chunk)
#define NCHUNK 4                 // 32 channels / 8 per chunk
#define NXCD 8

// ---------------------------------------------------------------------------
// Prologue: per (b, src_view i=1..4) compute P = src_proj_new @ inv(ref_proj_new)
// ---------------------------------------------------------------------------
__global__ void proj_kernel(const float* __restrict__ proj, float* __restrict__ out12) {
    int t = blockIdx.x * blockDim.x + threadIdx.x;
    if (t >= Bn * (Vn - 1)) return;
    int b = t / (Vn - 1);
    int i = t % (Vn - 1) + 1;

    const float* pb = proj + (size_t)b * Vn * 2 * 16;

    double refm[16], srcm[16];
    {
        const float* E = pb + 0 * 32 + 0;
        const float* K = pb + 0 * 32 + 16;
        for (int r = 0; r < 3; r++)
            for (int c = 0; c < 4; c++) {
                double s = 0.0;
                for (int k = 0; k < 3; k++) s += (double)K[r*4+k] * (double)E[k*4+c];
                refm[r*4+c] = s;
            }
        for (int c = 0; c < 4; c++) refm[12+c] = (double)E[12+c];
    }
    {
        const float* E = pb + i * 32 + 0;
        const float* K = pb + i * 32 + 16;
        for (int r = 0; r < 3; r++)
            for (int c = 0; c < 4; c++) {
                double s = 0.0;
                for (int k = 0; k < 3; k++) s += (double)K[r*4+k] * (double)E[k*4+c];
                srcm[r*4+c] = s;
            }
        for (int c = 0; c < 4; c++) srcm[12+c] = (double)E[12+c];
    }

    double a[16], inv[16];
    for (int k = 0; k < 16; k++) { a[k] = refm[k]; inv[k] = 0.0; }
    inv[0] = inv[5] = inv[10] = inv[15] = 1.0;
    for (int col = 0; col < 4; col++) {
        int piv = col; double best = fabs(a[col*4+col]);
        for (int r = col + 1; r < 4; r++) {
            double v = fabs(a[r*4+col]);
            if (v > best) { best = v; piv = r; }
        }
        if (piv != col) {
            for (int c = 0; c < 4; c++) {
                double tmp = a[col*4+c]; a[col*4+c] = a[piv*4+c]; a[piv*4+c] = tmp;
                tmp = inv[col*4+c]; inv[col*4+c] = inv[piv*4+c]; inv[piv*4+c] = tmp;
            }
        }
        double rd = 1.0 / a[col*4+col];
        for (int c = 0; c < 4; c++) { a[col*4+c] *= rd; inv[col*4+c] *= rd; }
        for (int r = 0; r < 4; r++) {
            if (r == col) continue;
            double f = a[r*4+col];
            for (int c = 0; c < 4; c++) { a[r*4+c] -= f * a[col*4+c]; inv[r*4+c] -= f * inv[col*4+c]; }
        }
    }

    double P[16];
    for (int r = 0; r < 4; r++)
        for (int c = 0; c < 4; c++) {
            double s = 0.0;
            for (int k = 0; k < 4; k++) s += srcm[r*4+k] * inv[k*4+c];
            P[r*4+c] = s;
        }

    float* o = out12 + t * 12;
    o[0] = (float)P[0];  o[1] = (float)P[1];  o[2]  = (float)P[2];
    o[3] = (float)P[4];  o[4] = (float)P[5];  o[5]  = (float)P[6];
    o[6] = (float)P[8];  o[7] = (float)P[9];  o[8]  = (float)P[10];
    o[9] = (float)P[3];  o[10] = (float)P[7]; o[11] = (float)P[11];
}

// ---------------------------------------------------------------------------
// Main kernel: channel-chunk loop split ACROSS BLOCKS.
//
// Round-0 diagnosis: VALUBusy 20.6%, HBM 32%, Occupancy 55% -> latency-bound,
// and occupancy was hard-capped by grid size (1280 blocks x 4 waves = 5120
// waves vs 8192 slots = 62.5%). The 4 channel chunks per thread are fully
// independent work -> make them blocks: grid = 4b x 4chunk x 320 = 5120
// blocks = 20480 waves (2.5x device capacity).
//
// XCD-banded mapping: block n is dispatched to XCD n%8 (round-robin). We make
// xcd = bid&7 choose which two (b,chunk) pairs that XCD owns, and s = bid>>3
// walk the 320 pixel-blocks of each pair IN ROW ORDER. Vertically adjacent
// pixel-blocks (which share one bilinear src row per view/channel) therefore
// hit the SAME per-XCD L2 -> recovers the ~2x row re-fetch seen in FETCH_SIZE
// (705 MB vs ~218 MB ideal).
//
// Per-thread body is the verified single-c0 iteration:
//  * b,chunk wave-uniform -> P12 reads are s_loads.
//  * Bilinear: clamped patch origin + weight remap; corners are
//    immediate-offset loads (+4B/+1280B/+1284B).
//  * ~40 VGPR -> fits the 64-VGPR cap of __launch_bounds__(256,8).
// ---------------------------------------------------------------------------
__global__ __launch_bounds__(256, 8) void cost_kernel(
    const float* __restrict__ depth_values,
    const float* __restrict__ features,
    const float* __restrict__ depth_interval,
    const float* __restrict__ view_weights,
    const float* __restrict__ P12,
    float* __restrict__ sim_out,
    float* __restrict__ samp_out)
{
    int bid  = blockIdx.x;            // 0..5119
    int xcd  = bid & (NXCD - 1);      // physical XCD under round-robin dispatch
    int s    = bid >> 3;              // 0..639 sequence within the XCD
    int half = (s >= PIXBLK) ? 1 : 0;
    int pair = xcd * 2 + half;        // 0..15 = (b, chunk)
    int pb   = s - half * PIXBLK;     // 0..319 pixel-block, row-ordered
    int b     = pair >> 2;            // wave-uniform
    int chunk = pair & 3;             // wave-uniform
    int c0    = chunk * 8;

    int pix = pb * 256 + threadIdx.x;
    int h   = pix / Ww;
    int w   = pix - h * Ww;

    float inv_d = 1.0f / depth_values[b * HW + pix];
    float itv   = depth_interval[b * HW + pix];
    float dmin  = inv_d - 2.0f * itv;
    float step  = (4.0f * itv) / 3.0f;

    float depth[DD];
    #pragma unroll
    for (int d = 0; d < DD; d++) {
        float sdi = dmin + (float)d * step;
        depth[d] = 1.0f / sdi;
    }
    if (chunk == 0) {                 // samples written exactly once per (b,pix)
        #pragma unroll
        for (int d = 0; d < DD; d++)
            samp_out[((size_t)b * DD + d) * HW + pix] = depth[d];
    }

    float vw[Vn - 1];
    float wsum = 0.0f;
    #pragma unroll
    for (int i = 0; i < Vn - 1; i++) {
        vw[i] = view_weights[((size_t)b * (Vn - 1) + i) * HW + pix];
        wsum += vw[i];
    }
    float dn = 1.0f / (wsum + 1e-6f);

    const float xf = (float)w, yf = (float)h;
    const float* refp = features + (size_t)b * Vn * Cc * HW + pix;
    float* so_base = sim_out + (size_t)b * (GG * DD) * HW + pix;

    float ref8[8];
    #pragma unroll
    for (int j = 0; j < 8; j++) ref8[j] = refp[(size_t)(c0 + j) * HW];

    float acc[2][DD];
    #pragma unroll
    for (int g2 = 0; g2 < 2; g2++)
        #pragma unroll
        for (int d = 0; d < DD; d++) acc[g2][d] = 0.0f;

    #pragma unroll 1
    for (int i = 0; i < Vn - 1; i++) {
        const float* P = P12 + (b * (Vn - 1) + i) * 12;   // uniform -> s_load
        float rx = P[0] * xf + P[1] * yf + P[2];
        float ry = P[3] * xf + P[4] * yf + P[5];
        float rz = P[6] * xf + P[7] * yf + P[8];
        float tx = P[9], ty = P[10], tz = P[11];

        float scale = 0.25f * vw[i];
        const float* src = features + ((size_t)(b * Vn) + (i + 1)) * Cc * HW
                         + (size_t)c0 * HW;

        #pragma unroll
        for (int d = 0; d < DD; d++) {
            float D  = depth[d];
            float px = rx * D + tx;
            float py = ry * D + ty;
            float pz = rz * D + tz;
            float rpz = 1.0f / pz;
            float gx = px * rpz;
            float gy = py * rpz;

            float x0f = floorf(gx);
            float y0f = floorf(gy);
            float wx1 = gx - x0f;
            float wy1 = gy - y0f;
            float wx0 = 1.0f - wx1;
            float wy0 = 1.0f - wy1;

            float xbf = fminf(fmaxf(x0f, 0.0f), (float)(Ww - 2));
            float ybf = fminf(fmaxf(y0f, 0.0f), (float)(Hh - 2));
            float dxf = x0f - xbf;
            float dyf = y0f - ybf;

            float pcx0 = (dxf == 0.0f) ? wx0 : ((dxf == -1.0f) ? wx1 : 0.0f);
            float pcx1 = (dxf == 0.0f) ? wx1 : ((dxf ==  1.0f) ? wx0 : 0.0f);
            float pcy0 = (dyf == 0.0f) ? wy0 : ((dyf == -1.0f) ? wy1 : 0.0f);
            float pcy1 = (dyf == 0.0f) ? wy1 : ((dyf ==  1.0f) ? wy0 : 0.0f);

            float W00 = pcx0 * pcy0 * scale;
            float W10 = pcx1 * pcy0 * scale;
            float W01 = pcx0 * pcy1 * scale;
            float W11 = pcx1 * pcy1 * scale;

            int o00 = (int)ybf * Ww + (int)xbf;

            #pragma unroll
            for (int j = 0; j < 8; j++) {
                const float* p = src + (size_t)j * HW + o00;
                float val = W00 * p[0] + W10 * p[1] + W01 * p[Ww] + W11 * p[Ww + 1];
                acc[j >> 2][d] += val * ref8[j];
            }
        }
    }

    // similarity index k = g*DD + d, g = c0/4 + g2
    #pragma unroll
    for (int g2 = 0; g2 < 2; g2++)
        #pragma unroll
        for (int d = 0; d < DD; d++)
            so_base[(size_t)(((c0 >> 2) + g2) * DD + d) * HW] = acc[g2][d] * dn;
}

extern "C" void kernel_launch(void* const* d_in, const int* in_sizes, int n_in,
                              void* d_out, int out_size, void* d_ws, size_t ws_size,
                              hipStream_t stream) {
    const float* depth_values   = (const float*)d_in[0];
    const float* features       = (const float*)d_in[1];
    const float* projm          = (const float*)d_in[2];
    const float* depth_interval = (const float*)d_in[3];
    const float* view_weights   = (const float*)d_in[6];

    float* out      = (float*)d_out;
    float* sim_out  = out;                              // (B, G*DD, H, W)
    float* samp_out = out + (size_t)Bn * GG * DD * HW;  // (B, DD, H, W)
    float* P12      = (float*)d_ws;                     // 16 x 12 floats

    proj_kernel<<<1, 64, 0, stream>>>(projm, P12);
    cost_kernel<<<Bn * NCHUNK * PIXBLK, 256, 0, stream>>>(
        depth_values, features, depth_interval, view_weights, P12, sim_out, samp_out);
}

// Round 3
// 540.554 us; speedup vs baseline: 1.3063x; 1.3063x over previous
//
#include <hip/hip_runtime.h>
#include <math.h>

#define Bn 4
#define Vn 5
#define Cc 32
#define Hh 256
#define Ww 320
#define DD 4
#define GG 8
#define HW (Hh*Ww)
#define BLOCKS_PER_B (HW/256)    // 320
#define NXCD 8
#define BAND (Bn * BLOCKS_PER_B / NXCD)   // 160 pixel-blocks per XCD band

// ---------------------------------------------------------------------------
// Prologue: per (b, src_view i=1..4) compute P = src_proj_new @ inv(ref_proj_new)
// ---------------------------------------------------------------------------
__global__ void proj_kernel(const float* __restrict__ proj, float* __restrict__ out12) {
    int t = blockIdx.x * blockDim.x + threadIdx.x;
    if (t >= Bn * (Vn - 1)) return;
    int b = t / (Vn - 1);
    int i = t % (Vn - 1) + 1;

    const float* pb = proj + (size_t)b * Vn * 2 * 16;

    double refm[16], srcm[16];
    {
        const float* E = pb + 0 * 32 + 0;
        const float* K = pb + 0 * 32 + 16;
        for (int r = 0; r < 3; r++)
            for (int c = 0; c < 4; c++) {
                double s = 0.0;
                for (int k = 0; k < 3; k++) s += (double)K[r*4+k] * (double)E[k*4+c];
                refm[r*4+c] = s;
            }
        for (int c = 0; c < 4; c++) refm[12+c] = (double)E[12+c];
    }
    {
        const float* E = pb + i * 32 + 0;
        const float* K = pb + i * 32 + 16;
        for (int r = 0; r < 3; r++)
            for (int c = 0; c < 4; c++) {
                double s = 0.0;
                for (int k = 0; k < 3; k++) s += (double)K[r*4+k] * (double)E[k*4+c];
                srcm[r*4+c] = s;
            }
        for (int c = 0; c < 4; c++) srcm[12+c] = (double)E[12+c];
    }

    double a[16], inv[16];
    for (int k = 0; k < 16; k++) { a[k] = refm[k]; inv[k] = 0.0; }
    inv[0] = inv[5] = inv[10] = inv[15] = 1.0;
    for (int col = 0; col < 4; col++) {
        int piv = col; double best = fabs(a[col*4+col]);
        for (int r = col + 1; r < 4; r++) {
            double v = fabs(a[r*4+col]);
            if (v > best) { best = v; piv = r; }
        }
        if (piv != col) {
            for (int c = 0; c < 4; c++) {
                double tmp = a[col*4+c]; a[col*4+c] = a[piv*4+c]; a[piv*4+c] = tmp;
                tmp = inv[col*4+c]; inv[col*4+c] = inv[piv*4+c]; inv[piv*4+c] = tmp;
            }
        }
        double rd = 1.0 / a[col*4+col];
        for (int c = 0; c < 4; c++) { a[col*4+c] *= rd; inv[col*4+c] *= rd; }
        for (int r = 0; r < 4; r++) {
            if (r == col) continue;
            double f = a[r*4+col];
            for (int c = 0; c < 4; c++) { a[r*4+c] -= f * a[col*4+c]; inv[r*4+c] -= f * inv[col*4+c]; }
        }
    }

    double P[16];
    for (int r = 0; r < 4; r++)
        for (int c = 0; c < 4; c++) {
            double s = 0.0;
            for (int k = 0; k < 4; k++) s += srcm[r*4+k] * inv[k*4+c];
            P[r*4+c] = s;
        }

    float* o = out12 + t * 12;
    o[0] = (float)P[0];  o[1] = (float)P[1];  o[2]  = (float)P[2];
    o[3] = (float)P[4];  o[4] = (float)P[5];  o[5]  = (float)P[6];
    o[6] = (float)P[8];  o[7] = (float)P[9];  o[8]  = (float)P[10];
    o[9] = (float)P[3];  o[10] = (float)P[7]; o[11] = (float)P[11];
}

// ---------------------------------------------------------------------------
// Main kernel = the VERIFIED round-0 body (303 us, 40 VGPR, no scratch) with
// exactly two changes:
//
// 1. XCD-banded block->pixel mapping. Round-0 had bid = b*320+pb with
//    round-robin dispatch -> vertically adjacent pixel-blocks (which share
//    bilinear src rows: row pair + 2-5 px depth parallax => each src row is
//    read by ~6 neighboring row-blocks) landed on DIFFERENT per-XCD L2s ->
//    FETCH_SIZE 688 MB vs ~226 MB ideal. Now xcd = bid&7 owns the contiguous
//    quarter-image band unit = xcd*160 + (bid>>3); all vertical sharers are
//    on one XCD and phase-aligned (per-phase footprint ~8ch x band-rows x
//    1280B ~ 1.3 MB < 4 MB L2).
//    Round-2 lesson: occupancy is NOT the binding constraint (83% occupancy
//    ran 1.6x SLOWER with +320 MB writes); traffic is. Grid stays 1280.
//
// 2. Nontemporal sim/samp stores: output is never re-read; keep the 47 MB of
//    write data from evicting gather lines in L2.
//
// Everything else (launch bounds 256x6, c0-chunk loop, clamped-patch
// bilinear, register budget) is byte-identical to the verified round-0.
// ---------------------------------------------------------------------------
__global__ __launch_bounds__(256, 6) void cost_kernel(
    const float* __restrict__ depth_values,
    const float* __restrict__ features,
    const float* __restrict__ depth_interval,
    const float* __restrict__ view_weights,
    const float* __restrict__ P12,
    float* __restrict__ sim_out,
    float* __restrict__ samp_out)
{
    int bid  = blockIdx.x;               // 0..1279
    int xcd  = bid & (NXCD - 1);         // physical XCD under round-robin dispatch
    int s    = bid >> 3;                 // 0..159 sequence within the XCD
    int unit = xcd * BAND + s;           // contiguous band per XCD
    int b    = unit / BLOCKS_PER_B;      // wave-uniform
    int pb   = unit - b * BLOCKS_PER_B;  // row-ordered pixel-block
    int pix  = pb * 256 + threadIdx.x;
    int h    = pix / Ww;
    int w    = pix - h * Ww;

    float inv_d = 1.0f / depth_values[b * HW + pix];
    float itv   = depth_interval[b * HW + pix];
    float dmin  = inv_d - 2.0f * itv;
    float step  = (4.0f * itv) / 3.0f;

    float depth[DD];
    #pragma unroll
    for (int d = 0; d < DD; d++) {
        float sdi = dmin + (float)d * step;
        depth[d] = 1.0f / sdi;
        __builtin_nontemporal_store(depth[d],
            &samp_out[((size_t)b * DD + d) * HW + pix]);
    }

    float vw[Vn - 1];
    float wsum = 0.0f;
    #pragma unroll
    for (int i = 0; i < Vn - 1; i++) {
        vw[i] = view_weights[((size_t)b * (Vn - 1) + i) * HW + pix];
        wsum += vw[i];
    }
    float dn = 1.0f / (wsum + 1e-6f);

    const float xf = (float)w, yf = (float)h;
    const float* refp = features + (size_t)b * Vn * Cc * HW + pix;
    float* so_base = sim_out + (size_t)b * (GG * DD) * HW + pix;

    #pragma unroll 1
    for (int c0 = 0; c0 < Cc; c0 += 8) {
        float ref8[8];
        #pragma unroll
        for (int j = 0; j < 8; j++) ref8[j] = refp[(size_t)(c0 + j) * HW];

        float acc[2][DD];
        #pragma unroll
        for (int g2 = 0; g2 < 2; g2++)
            #pragma unroll
            for (int d = 0; d < DD; d++) acc[g2][d] = 0.0f;

        #pragma unroll 1
        for (int i = 0; i < Vn - 1; i++) {
            const float* P = P12 + (b * (Vn - 1) + i) * 12;   // uniform -> s_load
            float rx = P[0] * xf + P[1] * yf + P[2];
            float ry = P[3] * xf + P[4] * yf + P[5];
            float rz = P[6] * xf + P[7] * yf + P[8];
            float tx = P[9], ty = P[10], tz = P[11];

            float scale = 0.25f * vw[i];
            const float* src = features + ((size_t)(b * Vn) + (i + 1)) * Cc * HW
                             + (size_t)c0 * HW;

            #pragma unroll
            for (int d = 0; d < DD; d++) {
                float D  = depth[d];
                float px = rx * D + tx;
                float py = ry * D + ty;
                float pz = rz * D + tz;
                float rpz = 1.0f / pz;
                float gx = px * rpz;
                float gy = py * rpz;

                float x0f = floorf(gx);
                float y0f = floorf(gy);
                float wx1 = gx - x0f;
                float wy1 = gy - y0f;
                float wx0 = 1.0f - wx1;
                float wy0 = 1.0f - wy1;

                float xbf = fminf(fmaxf(x0f, 0.0f), (float)(Ww - 2));
                float ybf = fminf(fmaxf(y0f, 0.0f), (float)(Hh - 2));
                float dxf = x0f - xbf;
                float dyf = y0f - ybf;

                float pcx0 = (dxf == 0.0f) ? wx0 : ((dxf == -1.0f) ? wx1 : 0.0f);
                float pcx1 = (dxf == 0.0f) ? wx1 : ((dxf ==  1.0f) ? wx0 : 0.0f);
                float pcy0 = (dyf == 0.0f) ? wy0 : ((dyf == -1.0f) ? wy1 : 0.0f);
                float pcy1 = (dyf == 0.0f) ? wy1 : ((dyf ==  1.0f) ? wy0 : 0.0f);

                float W00 = pcx0 * pcy0 * scale;
                float W10 = pcx1 * pcy0 * scale;
                float W01 = pcx0 * pcy1 * scale;
                float W11 = pcx1 * pcy1 * scale;

                int o00 = (int)ybf * Ww + (int)xbf;

                #pragma unroll
                for (int j = 0; j < 8; j++) {
                    const float* p = src + (size_t)j * HW + o00;
                    float val = W00 * p[0] + W10 * p[1] + W01 * p[Ww] + W11 * p[Ww + 1];
                    acc[j >> 2][d] += val * ref8[j];
                }
            }
        }

        // similarity index k = g*DD + d, g = c0/4 + g2
        #pragma unroll
        for (int g2 = 0; g2 < 2; g2++)
            #pragma unroll
            for (int d = 0; d < DD; d++)
                __builtin_nontemporal_store(acc[g2][d] * dn,
                    &so_base[(size_t)(((c0 >> 2) + g2) * DD + d) * HW]);
    }
}

extern "C" void kernel_launch(void* const* d_in, const int* in_sizes, int n_in,
                              void* d_out, int out_size, void* d_ws, size_t ws_size,
                              hipStream_t stream) {
    const float* depth_values   = (const float*)d_in[0];
    const float* features       = (const float*)d_in[1];
    const float* projm          = (const float*)d_in[2];
    const float* depth_interval = (const float*)d_in[3];
    const float* view_weights   = (const float*)d_in[6];

    float* out      = (float*)d_out;
    float* sim_out  = out;                              // (B, G*DD, H, W)
    float* samp_out = out + (size_t)Bn * GG * DD * HW;  // (B, DD, H, W)
    float* P12      = (float*)d_ws;                     // 16 x 12 floats

    proj_kernel<<<1, 64, 0, stream>>>(projm, P12);
    cost_kernel<<<Bn * BLOCKS_PER_B, 256, 0, stream>>>(
        depth_values, features, depth_interval, view_weights, P12, sim_out, samp_out);
}